// Round 6
// baseline (305.379 us; speedup 1.0000x reference)
//
#include <hip/hip_runtime.h>
#include <cstdint>
#include <cstddef>

typedef __attribute__((ext_vector_type(8))) short short8;
typedef __attribute__((ext_vector_type(4))) float f32x4;
typedef unsigned int u32;

#define MFMA_BF16(a, b, c) __builtin_amdgcn_mfma_f32_16x16x32_bf16((a), (b), (c), 0, 0, 0)

// ---------------------------------------------------------------------------
// helpers
// ---------------------------------------------------------------------------
__device__ __forceinline__ void async16(const void* g, void* l) {
  __builtin_amdgcn_global_load_lds(
      (const __attribute__((address_space(1))) u32*)g,
      (__attribute__((address_space(3))) u32*)l, 16, 0, 0);
}

__device__ __forceinline__ short f2bf(float f) {
  u32 u = __builtin_bit_cast(u32, f);
  u += 0x7fffu + ((u >> 16) & 1u);  // round-to-nearest-even
  return (short)(u >> 16);
}

// truncating pack: [bf16(lo) | bf16(hi)<<16] in ONE v_perm_b32
__device__ __forceinline__ u32 pack_bf16_trunc(float lo, float hi) {
  return __builtin_amdgcn_perm(__builtin_bit_cast(u32, hi),
                               __builtin_bit_cast(u32, lo), 0x07060302u);
}

// ---------------------------------------------------------------------------
// cast fp32 -> bf16; scale variant folds attn scale into q-rows of w_attn
// ---------------------------------------------------------------------------
__global__ void cast_bf16_kernel(const float* __restrict__ in,
                                 short* __restrict__ out, int n4) {
  int i = blockIdx.x * blockDim.x + threadIdx.x;
  if (i < n4) {
    float4 v = ((const float4*)in)[i];
    short4 r;
    r.x = f2bf(v.x); r.y = f2bf(v.y); r.z = f2bf(v.z); r.w = f2bf(v.w);
    ((short4*)out)[i] = r;
  }
}

// w_attn [3072][1024]; rows < 1024 (q) scaled by 1/sqrt(64)*log2(e)
__global__ void cast_wattn_kernel(const float* __restrict__ in,
                                  short* __restrict__ out, int n4) {
  int i = blockIdx.x * blockDim.x + threadIdx.x;
  if (i < n4) {
    const float sc = (i * 4 < 1024 * 1024) ? 0.18033688011112042f : 1.0f;
    float4 v = ((const float4*)in)[i];
    short4 r;
    r.x = f2bf(v.x * sc); r.y = f2bf(v.y * sc);
    r.z = f2bf(v.z * sc); r.w = f2bf(v.w * sc);
    ((short4*)out)[i] = r;
  }
}

// ---------------------------------------------------------------------------
// C[M][N] = A[M][K] * Bt[N][K]^T   (bf16-as-short in, fp32 accumulate)
// m97 structure: 128x128 tile, BK=32, global_load_lds w=16, 16x16x32 MFMA.
// r6: (a) XCD-aware block swizzle — requires gridDim.y == 64: each XCD owns
// 8 consecutive m-tiles (A slice 2 MB L2-resident), n-tiles walked with
// 8-block B-tile reuse. (b) conflict-free LDS layout: slot ci =
// (rt<<6)|(ch<<4)|lo holds T[rt*16+lo][k0+ch*8..+7]; frag reads at byte
// addr quad*256 + l15*16 -> 2-way bank alias = free (m136).
// ---------------------------------------------------------------------------
template <bool OUT_BF16>
__global__ __launch_bounds__(256) void gemm_bt_kernel(
    const short* __restrict__ A, const short* __restrict__ Bt,
    void* __restrict__ Cv, int M, int N, int K) {
  __shared__ __align__(16) short As[128 * 32];
  __shared__ __align__(16) short Bs[128 * 32];

  const int tid  = threadIdx.x;
  const int lane = tid & 63;
  const int wave = tid >> 6;
  const int quad = lane >> 4;
  const int l15  = lane & 15;

  // XCD swizzle (gridDim.y == 64): linear id -> (bx, by)
  const int id  = blockIdx.y * gridDim.x + blockIdx.x;
  const int xcd = id & 7;
  const int j   = id >> 3;
  const int by  = xcd * 8 + (j & 7);
  const int bx  = j >> 3;
  const int bm  = by * 128;
  const int bn  = bx * 128;

  const int wm = (wave >> 1) * 64;
  const int wn = (wave & 1) * 64;
  const int wr = (wave >> 1) * 4;   // wm/16
  const int wc = (wave & 1) * 4;    // wn/16

  f32x4 acc[4][4];
#pragma unroll
  for (int i = 0; i < 4; ++i)
#pragma unroll
    for (int jj = 0; jj < 4; ++jj) acc[i][jj] = (f32x4){0.f, 0.f, 0.f, 0.f};

  // staging: slot ci -> rt=ci>>6, ch=(ci>>4)&3, lo=ci&15; dst shorts ci*8.
  // per 64-lane wave instr: 16 rows x 64 B contiguous (coalescing preserved)
  const int ci0 = tid, ci1 = tid + 256;
  const int ro0 = ((ci0 >> 6) << 4) | (ci0 & 15), co0 = ((ci0 >> 4) & 3) * 8;
  const int ro1 = ((ci1 >> 6) << 4) | (ci1 & 15), co1 = ((ci1 >> 4) & 3) * 8;
  const short* ga0 = A  + (size_t)(bm + ro0) * K + co0;
  const short* ga1 = A  + (size_t)(bm + ro1) * K + co1;
  const short* gb0 = Bt + (size_t)(bn + ro0) * K + co0;
  const short* gb1 = Bt + (size_t)(bn + ro1) * K + co1;

  for (int k0 = 0; k0 < K; k0 += 32) {
    __syncthreads();
    async16(ga0 + k0, &As[ci0 * 8]);
    async16(ga1 + k0, &As[ci1 * 8]);
    async16(gb0 + k0, &Bs[ci0 * 8]);
    async16(gb1 + k0, &Bs[ci1 * 8]);
    __syncthreads();

    short8 af[4], bf[4];
#pragma unroll
    for (int mt = 0; mt < 4; ++mt)
      af[mt] = *(const short8*)&As[(wr + mt) * 512 + quad * 128 + l15 * 8];
#pragma unroll
    for (int nt = 0; nt < 4; ++nt)
      bf[nt] = *(const short8*)&Bs[(wc + nt) * 512 + quad * 128 + l15 * 8];
#pragma unroll
    for (int mt = 0; mt < 4; ++mt)
#pragma unroll
      for (int nt = 0; nt < 4; ++nt)
        acc[mt][nt] = MFMA_BF16(af[mt], bf[nt], acc[mt][nt]);
  }

  // epilogue: C/D layout col = lane&15, row = quad*4 + reg
#pragma unroll
  for (int mt = 0; mt < 4; ++mt) {
    const int r0 = bm + wm + mt * 16 + quad * 4;
#pragma unroll
    for (int nt = 0; nt < 4; ++nt) {
      const int c = bn + wn + nt * 16 + l15;
#pragma unroll
      for (int reg = 0; reg < 4; ++reg) {
        float v = acc[mt][nt][reg];
        if (OUT_BF16)
          ((short*)Cv)[(size_t)(r0 + reg) * N + c] = f2bf(v);
        else
          ((float*)Cv)[(size_t)(r0 + reg) * N + c] = v;
      }
    }
  }
}

// ---------------------------------------------------------------------------
// V transpose: qkv v-part [B*T][h*64+d] -> vt [bh*64+d][T]   (bf16 shorts)
// (unchanged — known-good)
// ---------------------------------------------------------------------------
__global__ __launch_bounds__(256) void vtrans_kernel(
    const short* __restrict__ qkv, short* __restrict__ vt) {
  __shared__ __align__(16) short Ts[64 * 80];
  const int t0 = blockIdx.x * 64;
  const int bh = blockIdx.y;
  const int b = bh >> 4, h = bh & 15;
  const int tid = threadIdx.x;
#pragma unroll
  for (int it = 0; it < 2; ++it) {
    const int ci = tid + it * 256;
    const int t = ci >> 3, cw = ci & 7;
    short8 v = *(const short8*)(qkv + (size_t)(b * 2048 + t0 + t) * 3072 +
                                2048 + h * 64 + cw * 8);
    *(short8*)&Ts[t * 80 + cw * 8] = v;
  }
  __syncthreads();
#pragma unroll
  for (int it = 0; it < 2; ++it) {
    const int ci = tid + it * 256;
    const int d = ci >> 3, c2 = ci & 7;
    short tmp[8];
#pragma unroll
    for (int j = 0; j < 8; ++j) tmp[j] = Ts[(c2 * 8 + j) * 80 + d];
    *(short8*)(vt + (size_t)(bh * 64 + d) * 2048 + t0 + c2 * 8) =
        *(short8*)tmp;
  }
}

// ---------------------------------------------------------------------------
// Causal flash attention (unchanged from r5 — known-good).
// ---------------------------------------------------------------------------
__global__ __launch_bounds__(256, 2) void attn_kernel(
    const short* __restrict__ qkv, const short* __restrict__ vt,
    short* __restrict__ y) {
  __shared__ __align__(16) short Ks[2][4096];  // 8 KB per buf
  __shared__ __align__(16) short Vs[2][4096];
  __shared__ __align__(16) short Ps[4][1024];  // per-wave P / epilogue

  const int bh    = blockIdx.x;     // 0..63  (XCD = bh % 8 for all pairi)
  const int pairi = blockIdx.y;     // 0..7
  const int b = bh >> 4, h = bh & 15;
  const int tid  = threadIdx.x;
  const int lane = tid & 63;
  const int wave = tid >> 6;
  const int quad = lane >> 4, l15 = lane & 15;
  const int base_row = b * 2048;
  short* Pw = &Ps[wave][0];

  // staging: slot ci -> (kk=ci>>8, nt=(ci>>6)&3, chunk=(ci>>4)&3, lo=ci&15)
  const int ci0 = tid, ci1 = tid + 256;
  const int ro0 = ((ci0 >> 6) & 3) * 16 + (ci0 & 15);   // row/d offset
  const int ro1 = ((ci1 >> 6) & 3) * 16 + (ci1 & 15);
  const int co0 = (ci0 >> 8) * 32 + ((ci0 >> 4) & 3) * 8;  // col/t offset
  const int co1 = (ci1 >> 8) * 32 + ((ci1 >> 4) & 3) * 8;
  const short* kbase0 = qkv + (size_t)(base_row + ro0) * 3072 + 1024 + h * 64 + co0;
  const short* kbase1 = qkv + (size_t)(base_row + ro1) * 3072 + 1024 + h * 64 + co1;
  const short* vbase0 = vt + (size_t)(bh * 64 + ro0) * 2048 + co0;
  const short* vbase1 = vt + (size_t)(bh * 64 + ro1) * 2048 + co1;

  for (int half = 0; half < 2; ++half) {
    const int qi  = half ? (15 - pairi) : pairi;
    const int r0  = qi * 128;
    const int nkt = 2 * qi + 2;
    const int qg0a = r0 + wave * 32;   // group 0 q-base (seq-relative)
    const int qg0b = qg0a + 16;        // group 1

    // Q fragments (B-operand): lane holds Q[q=l15][d=quad*8..+7] per half
    short8 qf[2][2];
#pragma unroll
    for (int g = 0; g < 2; ++g) {
      const short* qp = qkv +
          (size_t)(base_row + qg0a + g * 16 + l15) * 3072 + h * 64 + quad * 8;
      qf[g][0] = *(const short8*)qp;
      qf[g][1] = *(const short8*)(qp + 32);
    }
    float l_r[2] = {0.f, 0.f};
    f32x4 o[2][4];
#pragma unroll
    for (int g = 0; g < 2; ++g)
#pragma unroll
      for (int dt = 0; dt < 4; ++dt) o[g][dt] = (f32x4){0.f, 0.f, 0.f, 0.f};

    // prologue: stage kv-tile 0 into buffer 0
    async16(kbase0, &Ks[0][ci0 * 8]);
    async16(kbase1, &Ks[0][ci1 * 8]);
    async16(vbase0, &Vs[0][ci0 * 8]);
    async16(vbase1, &Vs[0][ci1 * 8]);

    for (int kt = 0; kt < nkt; ++kt) {
      const int kvb = kt * 64;
      __syncthreads();  // drains vmcnt -> buf[kt&1] ready; prev reads done

      // prefetch next tile into the other buffer
      if (kt + 1 < nkt) {
        const int nb = (kt + 1) & 1;
        const size_t koff = (size_t)(kvb + 64) * 3072;
        async16(kbase0 + koff, &Ks[nb][ci0 * 8]);
        async16(kbase1 + koff, &Ks[nb][ci1 * 8]);
        async16(vbase0 + kvb + 64, &Vs[nb][ci0 * 8]);
        async16(vbase1 + kvb + 64, &Vs[nb][ci1 * 8]);
      }
      const short* Kb = &Ks[kt & 1][0];
      const short* Vb = &Vs[kt & 1][0];

      // K frags (A-operand): conflict-free reads
      short8 kf[4][2];
#pragma unroll
      for (int nt = 0; nt < 4; ++nt) {
        kf[nt][0] = *(const short8*)&Kb[nt * 512 + quad * 128 + l15 * 8];
        kf[nt][1] = *(const short8*)&Kb[2048 + nt * 512 + quad * 128 + l15 * 8];
      }
      // V frags (A-operand): hoisted — read ONCE, shared by both groups
      short8 vf[4][2];
#pragma unroll
      for (int dt = 0; dt < 4; ++dt) {
        vf[dt][0] = *(const short8*)&Vb[dt * 512 + quad * 128 + l15 * 8];
        vf[dt][1] = *(const short8*)&Vb[2048 + dt * 512 + quad * 128 + l15 * 8];
      }

#pragma unroll
      for (int g = 0; g < 2; ++g) {
        const int qg0 = qg0a + g * 16;
        if (kvb > qg0 + 15) continue;  // group fully masked

        // S^T = K Q^T : lane gets S^T[kv=nt*16+quad*4+reg][q=l15]
        f32x4 s[4];
#pragma unroll
        for (int nt = 0; nt < 4; ++nt) {
          s[nt] = MFMA_BF16(kf[nt][0], qf[g][0], ((f32x4){0.f, 0.f, 0.f, 0.f}));
          s[nt] = MFMA_BF16(kf[nt][1], qf[g][1], s[nt]);
        }

        // p = exp2(s); mask only on diagonal tiles
        float p[4][4];
        if (kvb + 64 <= qg0) {
#pragma unroll
          for (int nt = 0; nt < 4; ++nt)
#pragma unroll
            for (int r = 0; r < 4; ++r)
              p[nt][r] = __builtin_amdgcn_exp2f(s[nt][r]);
        } else {
          const int qrel = qg0 + l15 - kvb;
#pragma unroll
          for (int nt = 0; nt < 4; ++nt)
#pragma unroll
            for (int r = 0; r < 4; ++r) {
              const int kvl = nt * 16 + quad * 4 + r;
              p[nt][r] = (kvl <= qrel) ? __builtin_amdgcn_exp2f(s[nt][r]) : 0.f;
            }
        }

        // row sum: 15 in-lane adds + 2 cross-quad shuffles
        float rs = ((p[0][0] + p[0][1]) + (p[0][2] + p[0][3])) +
                   ((p[1][0] + p[1][1]) + (p[1][2] + p[1][3])) +
                   ((p[2][0] + p[2][1]) + (p[2][2] + p[2][3])) +
                   ((p[3][0] + p[3][1]) + (p[3][2] + p[3][3]));
        rs += __shfl_xor(rs, 16);
        rs += __shfl_xor(rs, 32);
        l_r[g] += rs;

        // P -> LDS, layout [f][chunk][q]x16B; pair p0 = 8nt+2quad
#pragma unroll
        for (int nt = 0; nt < 4; ++nt) {
          u32 w0 = pack_bf16_trunc(p[nt][0], p[nt][1]);
          u32 w1 = pack_bf16_trunc(p[nt][2], p[nt][3]);
          const int p0 = 8 * nt + 2 * quad;
          u32* dst = (u32*)Pw + (p0 >> 4) * 256 + ((p0 >> 2) & 3) * 64 +
                     l15 * 4 + (p0 & 3);
          *(uint2*)dst = make_uint2(w0, w1);
        }
        // P frags (B-operand): contiguous b128, conflict-free
        short8 pf0 = *(const short8*)&Pw[quad * 128 + l15 * 8];
        short8 pf1 = *(const short8*)&Pw[512 + quad * 128 + l15 * 8];

        // O^T += V^T P^T : lane gets O^T[d=dt*16+quad*4+reg][q=l15]
#pragma unroll
        for (int dt = 0; dt < 4; ++dt) {
          o[g][dt] = MFMA_BF16(vf[dt][0], pf0, o[g][dt]);
          o[g][dt] = MFMA_BF16(vf[dt][1], pf1, o[g][dt]);
        }
      }
    }

    // epilogue: normalize, transpose via per-wave LDS, coalesced bf16 store
#pragma unroll
    for (int g = 0; g < 2; ++g) {
      const float inv = 1.f / l_r[g];
#pragma unroll
      for (int dt = 0; dt < 4; ++dt) {
        const int d = dt * 16 + quad * 4;
        u32 w0 = pack_bf16_trunc(o[g][dt][0] * inv, o[g][dt][1] * inv);
        u32 w1 = pack_bf16_trunc(o[g][dt][2] * inv, o[g][dt][3] * inv);
        *(uint2*)&Pw[(d >> 5) * 512 + l15 * 32 + (d & 31)] = make_uint2(w0, w1);
      }
      const int qq = lane >> 2, ck = lane & 3;
      const size_t yrow = (size_t)(base_row + qg0a + g * 16 + qq);
#pragma unroll
      for (int kkd = 0; kkd < 2; ++kkd) {
        short8 vv = *(const short8*)&Pw[kkd * 512 + qq * 32 + ck * 8];
        *(short8*)(y + yrow * 1024 + h * 64 + kkd * 32 + ck * 8) = vv;
      }
    }
    __syncthreads();  // all K/V/P reads of this half done before next prologue
  }
}

// ---------------------------------------------------------------------------
// launch
// ---------------------------------------------------------------------------
extern "C" void kernel_launch(void* const* d_in, const int* in_sizes, int n_in,
                              void* d_out, int out_size, void* d_ws,
                              size_t ws_size, hipStream_t stream) {
  const float* x  = (const float*)d_in[0];   // [4,2048,1024]
  const float* wa = (const float*)d_in[1];   // [3072,1024]
  const float* wp = (const float*)d_in[2];   // [1024,1024]
  float* out = (float*)d_out;                // [4,2048,1024] fp32

  char* ws = (char*)d_ws;
  short* xb  = (short*)(ws + 0);             // 16 MB (reused as vt later)
  short* wab = (short*)(ws + 16777216);      // 6 MB
  short* wpb = (short*)(ws + 23068672);      // 2 MB
  short* qkv = (short*)(ws + 25165824);      // 48 MB
  short* yb  = (short*)(ws + 75497472);      // 16 MB
  short* vtb = xb;  // x no longer needed after GEMM1; reuse its 16 MB

  cast_bf16_kernel <<<8192, 256, 0, stream>>>(x,  xb,  8388608 / 4);
  cast_wattn_kernel<<<3072, 256, 0, stream>>>(wa, wab, 3145728 / 4);
  cast_bf16_kernel <<<1024, 256, 0, stream>>>(wp, wpb, 1048576 / 4);

  // qkv = x @ w_attn^T (q pre-scaled): M=8192 N=3072 K=1024 -> bf16
  gemm_bt_kernel<true><<<dim3(3072 / 128, 8192 / 128), 256, 0, stream>>>(
      xb, wab, (void*)qkv, 8192, 3072, 1024);

  // v-part of qkv -> vt [bh*64+d][2048]
  vtrans_kernel<<<dim3(32, 64), 256, 0, stream>>>(qkv, vtb);

  // balanced causal flash attention -> y bf16 [8192,1024]
  attn_kernel<<<dim3(64, 8), 256, 0, stream>>>(qkv, vtb, yb);

  // out = y @ w_proj^T : M=8192 N=1024 K=1024 -> fp32
  gemm_bt_kernel<false><<<dim3(1024 / 128, 8192 / 128), 256, 0, stream>>>(
      yb, wpb, (void*)out, 8192, 1024, 1024);
}

// Round 7
// 261.507 us; speedup vs baseline: 1.1678x; 1.1678x over previous
//
#include <hip/hip_runtime.h>
#include <cstdint>
#include <cstddef>

typedef __attribute__((ext_vector_type(8))) short short8;
typedef __attribute__((ext_vector_type(4))) float f32x4;
typedef unsigned int u32;

#define MFMA_BF16(a, b, c) __builtin_amdgcn_mfma_f32_16x16x32_bf16((a), (b), (c), 0, 0, 0)

// ---------------------------------------------------------------------------
// helpers
// ---------------------------------------------------------------------------
__device__ __forceinline__ void async16(const void* g, void* l) {
  __builtin_amdgcn_global_load_lds(
      (const __attribute__((address_space(1))) u32*)g,
      (__attribute__((address_space(3))) u32*)l, 16, 0, 0);
}

__device__ __forceinline__ short f2bf(float f) {
  u32 u = __builtin_bit_cast(u32, f);
  u += 0x7fffu + ((u >> 16) & 1u);  // round-to-nearest-even
  return (short)(u >> 16);
}

// truncating pack: [bf16(lo) | bf16(hi)<<16] in ONE v_perm_b32
__device__ __forceinline__ u32 pack_bf16_trunc(float lo, float hi) {
  return __builtin_amdgcn_perm(__builtin_bit_cast(u32, hi),
                               __builtin_bit_cast(u32, lo), 0x07060302u);
}

// ---------------------------------------------------------------------------
// cast fp32 -> bf16; scale variant folds attn scale into q-rows of w_attn
// ---------------------------------------------------------------------------
__global__ void cast_bf16_kernel(const float* __restrict__ in,
                                 short* __restrict__ out, int n4) {
  int i = blockIdx.x * blockDim.x + threadIdx.x;
  if (i < n4) {
    float4 v = ((const float4*)in)[i];
    short4 r;
    r.x = f2bf(v.x); r.y = f2bf(v.y); r.z = f2bf(v.z); r.w = f2bf(v.w);
    ((short4*)out)[i] = r;
  }
}

// w_attn [3072][1024]; rows < 1024 (q) scaled by 1/sqrt(64)*log2(e)
__global__ void cast_wattn_kernel(const float* __restrict__ in,
                                  short* __restrict__ out, int n4) {
  int i = blockIdx.x * blockDim.x + threadIdx.x;
  if (i < n4) {
    const float sc = (i * 4 < 1024 * 1024) ? 0.18033688011112042f : 1.0f;
    float4 v = ((const float4*)in)[i];
    short4 r;
    r.x = f2bf(v.x * sc); r.y = f2bf(v.y * sc);
    r.z = f2bf(v.z * sc); r.w = f2bf(v.w * sc);
    ((short4*)out)[i] = r;
  }
}

// ---------------------------------------------------------------------------
// C[M][N] = A[M][K] * Bt[N][K]^T   (bf16-as-short in, fp32 accumulate)
// 128x128 tile, BK=32, global_load_lds w=16, 16x16x32 MFMA.
// XCD swizzle (needs gridDim.y==64): each XCD owns 8 consecutive m-tiles.
// LDS: XOR-chunk placement — slot s holds T[row=s>>2][chunk=(s&3)^((s>>3)&3)];
// staging lanes stay row-contiguous (4 lanes = one 64B line), frag reads at
// chunk quad^((l15>>1)&3) are 2-way bank-aliased = free (m136).
// ---------------------------------------------------------------------------
template <bool OUT_BF16>
__global__ __launch_bounds__(256) void gemm_bt_kernel(
    const short* __restrict__ A, const short* __restrict__ Bt,
    void* __restrict__ Cv, int M, int N, int K) {
  __shared__ __align__(16) short As[128 * 32];
  __shared__ __align__(16) short Bs[128 * 32];

  const int tid  = threadIdx.x;
  const int lane = tid & 63;
  const int wave = tid >> 6;
  const int quad = lane >> 4;
  const int l15  = lane & 15;

  // XCD swizzle (gridDim.y == 64): linear id -> (bx, by)
  const int id  = blockIdx.y * gridDim.x + blockIdx.x;
  const int xcd = id & 7;
  const int j   = id >> 3;
  const int by  = xcd * 8 + (j & 7);
  const int bx  = j >> 3;
  const int bm  = by * 128;
  const int bn  = bx * 128;

  const int wm = (wave >> 1) * 64;
  const int wn = (wave & 1) * 64;

  f32x4 acc[4][4];
#pragma unroll
  for (int i = 0; i < 4; ++i)
#pragma unroll
    for (int jj = 0; jj < 4; ++jj) acc[i][jj] = (f32x4){0.f, 0.f, 0.f, 0.f};

  // staging: slot s -> row=s>>2, chunk=(s&3)^((s>>3)&3); dst shorts s*8.
  // 4 consecutive lanes read one row's 4 chunks (permuted) = 64B line.
  const int s0 = tid, s1 = tid + 256;
  const int r0 = s0 >> 2, c0 = (s0 & 3) ^ ((s0 >> 3) & 3);
  const int r1 = s1 >> 2, c1 = (s1 & 3) ^ ((s1 >> 3) & 3);
  const short* ga0 = A  + (size_t)(bm + r0) * K + c0 * 8;
  const short* ga1 = A  + (size_t)(bm + r1) * K + c1 * 8;
  const short* gb0 = Bt + (size_t)(bn + r0) * K + c0 * 8;
  const short* gb1 = Bt + (size_t)(bn + r1) * K + c1 * 8;

  const int xr = (l15 >> 1) & 3;  // frag-read chunk XOR

  for (int k0 = 0; k0 < K; k0 += 32) {
    __syncthreads();
    async16(ga0 + k0, &As[s0 * 8]);
    async16(ga1 + k0, &As[s1 * 8]);
    async16(gb0 + k0, &Bs[s0 * 8]);
    async16(gb1 + k0, &Bs[s1 * 8]);
    __syncthreads();

    short8 af[4], bf[4];
#pragma unroll
    for (int mt = 0; mt < 4; ++mt)
      af[mt] = *(const short8*)&As[(wm + mt * 16 + l15) * 32 + (quad ^ xr) * 8];
#pragma unroll
    for (int nt = 0; nt < 4; ++nt)
      bf[nt] = *(const short8*)&Bs[(wn + nt * 16 + l15) * 32 + (quad ^ xr) * 8];
#pragma unroll
    for (int mt = 0; mt < 4; ++mt)
#pragma unroll
      for (int nt = 0; nt < 4; ++nt)
        acc[mt][nt] = MFMA_BF16(af[mt], bf[nt], acc[mt][nt]);
  }

  // epilogue: C/D layout col = lane&15, row = quad*4 + reg
#pragma unroll
  for (int mt = 0; mt < 4; ++mt) {
    const int r0e = bm + wm + mt * 16 + quad * 4;
#pragma unroll
    for (int nt = 0; nt < 4; ++nt) {
      const int c = bn + wn + nt * 16 + l15;
#pragma unroll
      for (int reg = 0; reg < 4; ++reg) {
        float v = acc[mt][nt][reg];
        if (OUT_BF16)
          ((short*)Cv)[(size_t)(r0e + reg) * N + c] = f2bf(v);
        else
          ((float*)Cv)[(size_t)(r0e + reg) * N + c] = v;
      }
    }
  }
}

// ---------------------------------------------------------------------------
// V transpose: qkv v-part [B*T][h*64+d] -> vt [bh*64+d][T]   (bf16 shorts)
// (unchanged — known-good)
// ---------------------------------------------------------------------------
__global__ __launch_bounds__(256) void vtrans_kernel(
    const short* __restrict__ qkv, short* __restrict__ vt) {
  __shared__ __align__(16) short Ts[64 * 80];
  const int t0 = blockIdx.x * 64;
  const int bh = blockIdx.y;
  const int b = bh >> 4, h = bh & 15;
  const int tid = threadIdx.x;
#pragma unroll
  for (int it = 0; it < 2; ++it) {
    const int ci = tid + it * 256;
    const int t = ci >> 3, cw = ci & 7;
    short8 v = *(const short8*)(qkv + (size_t)(b * 2048 + t0 + t) * 3072 +
                                2048 + h * 64 + cw * 8);
    *(short8*)&Ts[t * 80 + cw * 8] = v;
  }
  __syncthreads();
#pragma unroll
  for (int it = 0; it < 2; ++it) {
    const int ci = tid + it * 256;
    const int d = ci >> 3, c2 = ci & 7;
    short tmp[8];
#pragma unroll
    for (int j = 0; j < 8; ++j) tmp[j] = Ts[(c2 * 8 + j) * 80 + d];
    *(short8*)(vt + (size_t)(bh * 64 + d) * 2048 + t0 + c2 * 8) =
        *(short8*)tmp;
  }
}

// ---------------------------------------------------------------------------
// Causal flash attention, S^T form, no-max softmax, dbuf staging, XCD-local
// grid (64 bh, 8 pairi). r7: K/V tiles stored 64 rows x 128 B with XOR-chunk
// placement — slot s holds T[row=s>>3][chunk=(s&7)^(row&7)]; staging lanes
// row-contiguous (4 lanes = 64B line), frag reads at chunk
// (kk*4+quad)^(l15&7) are 2-way bank-aliased = free.
// ---------------------------------------------------------------------------
__global__ __launch_bounds__(256, 2) void attn_kernel(
    const short* __restrict__ qkv, const short* __restrict__ vt,
    short* __restrict__ y) {
  __shared__ __align__(16) short Ks[2][4096];  // [buf][row t][64 d]
  __shared__ __align__(16) short Vs[2][4096];  // [buf][row d][64 t]
  __shared__ __align__(16) short Ps[4][1024];  // per-wave P / epilogue

  const int bh    = blockIdx.x;     // 0..63  (XCD = bh % 8 for all pairi)
  const int pairi = blockIdx.y;     // 0..7
  const int b = bh >> 4, h = bh & 15;
  const int tid  = threadIdx.x;
  const int lane = tid & 63;
  const int wave = tid >> 6;
  const int quad = lane >> 4, l15 = lane & 15;
  const int base_row = b * 2048;
  short* Pw = &Ps[wave][0];

  // staging: slot s -> row=s>>3, chunk=(s&7)^(row&7); dst shorts s*8
  const int s0 = tid, s1 = tid + 256;
  const int r0s = s0 >> 3, c0s = (s0 & 7) ^ (r0s & 7);
  const int r1s = s1 >> 3, c1s = (s1 & 7) ^ (r1s & 7);
  const short* kbase0 = qkv + (size_t)(base_row + r0s) * 3072 + 1024 + h * 64 + c0s * 8;
  const short* kbase1 = qkv + (size_t)(base_row + r1s) * 3072 + 1024 + h * 64 + c1s * 8;
  const short* vbase0 = vt + (size_t)(bh * 64 + r0s) * 2048 + c0s * 8;
  const short* vbase1 = vt + (size_t)(bh * 64 + r1s) * 2048 + c1s * 8;

  const int xk = l15 & 7;  // frag-read chunk XOR

  for (int half = 0; half < 2; ++half) {
    const int qi  = half ? (15 - pairi) : pairi;
    const int r0  = qi * 128;
    const int nkt = 2 * qi + 2;
    const int qg0a = r0 + wave * 32;   // group 0 q-base (seq-relative)

    // Q fragments (B-operand): lane holds Q[q=l15][d=quad*8..+7] per half
    short8 qf[2][2];
#pragma unroll
    for (int g = 0; g < 2; ++g) {
      const short* qp = qkv +
          (size_t)(base_row + qg0a + g * 16 + l15) * 3072 + h * 64 + quad * 8;
      qf[g][0] = *(const short8*)qp;
      qf[g][1] = *(const short8*)(qp + 32);
    }
    float l_r[2] = {0.f, 0.f};
    f32x4 o[2][4];
#pragma unroll
    for (int g = 0; g < 2; ++g)
#pragma unroll
      for (int dt = 0; dt < 4; ++dt) o[g][dt] = (f32x4){0.f, 0.f, 0.f, 0.f};

    // prologue: stage kv-tile 0 into buffer 0
    async16(kbase0, &Ks[0][s0 * 8]);
    async16(kbase1, &Ks[0][s1 * 8]);
    async16(vbase0, &Vs[0][s0 * 8]);
    async16(vbase1, &Vs[0][s1 * 8]);

    for (int kt = 0; kt < nkt; ++kt) {
      const int kvb = kt * 64;
      __syncthreads();  // drains vmcnt -> buf[kt&1] ready; prev reads done

      // prefetch next tile into the other buffer
      if (kt + 1 < nkt) {
        const int nb = (kt + 1) & 1;
        const size_t koff = (size_t)(kvb + 64) * 3072;
        async16(kbase0 + koff, &Ks[nb][s0 * 8]);
        async16(kbase1 + koff, &Ks[nb][s1 * 8]);
        async16(vbase0 + kvb + 64, &Vs[nb][s0 * 8]);
        async16(vbase1 + kvb + 64, &Vs[nb][s1 * 8]);
      }
      const short* Kb = &Ks[kt & 1][0];
      const short* Vb = &Vs[kt & 1][0];

      // K frags (A-operand): row t=nt*16+l15, chunk (kk*4+quad)^xk
      short8 kf[4][2];
#pragma unroll
      for (int nt = 0; nt < 4; ++nt) {
        kf[nt][0] = *(const short8*)&Kb[(nt * 16 + l15) * 64 + ((quad) ^ xk) * 8];
        kf[nt][1] = *(const short8*)&Kb[(nt * 16 + l15) * 64 + ((4 + quad) ^ xk) * 8];
      }
      // V frags (A-operand): hoisted — read ONCE, shared by both groups
      short8 vf[4][2];
#pragma unroll
      for (int dt = 0; dt < 4; ++dt) {
        vf[dt][0] = *(const short8*)&Vb[(dt * 16 + l15) * 64 + ((quad) ^ xk) * 8];
        vf[dt][1] = *(const short8*)&Vb[(dt * 16 + l15) * 64 + ((4 + quad) ^ xk) * 8];
      }

#pragma unroll
      for (int g = 0; g < 2; ++g) {
        const int qg0 = qg0a + g * 16;
        if (kvb > qg0 + 15) continue;  // group fully masked

        // S^T = K Q^T : lane gets S^T[kv=nt*16+quad*4+reg][q=l15]
        f32x4 s[4];
#pragma unroll
        for (int nt = 0; nt < 4; ++nt) {
          s[nt] = MFMA_BF16(kf[nt][0], qf[g][0], ((f32x4){0.f, 0.f, 0.f, 0.f}));
          s[nt] = MFMA_BF16(kf[nt][1], qf[g][1], s[nt]);
        }

        // p = exp2(s); mask only on diagonal tiles
        float p[4][4];
        if (kvb + 64 <= qg0) {
#pragma unroll
          for (int nt = 0; nt < 4; ++nt)
#pragma unroll
            for (int r = 0; r < 4; ++r)
              p[nt][r] = __builtin_amdgcn_exp2f(s[nt][r]);
        } else {
          const int qrel = qg0 + l15 - kvb;
#pragma unroll
          for (int nt = 0; nt < 4; ++nt)
#pragma unroll
            for (int r = 0; r < 4; ++r) {
              const int kvl = nt * 16 + quad * 4 + r;
              p[nt][r] = (kvl <= qrel) ? __builtin_amdgcn_exp2f(s[nt][r]) : 0.f;
            }
        }

        // row sum: 15 in-lane adds + 2 cross-quad shuffles
        float rs = ((p[0][0] + p[0][1]) + (p[0][2] + p[0][3])) +
                   ((p[1][0] + p[1][1]) + (p[1][2] + p[1][3])) +
                   ((p[2][0] + p[2][1]) + (p[2][2] + p[2][3])) +
                   ((p[3][0] + p[3][1]) + (p[3][2] + p[3][3]));
        rs += __shfl_xor(rs, 16);
        rs += __shfl_xor(rs, 32);
        l_r[g] += rs;

        // P -> LDS, layout [f][chunk][q]x16B; pair p0 = 8nt+2quad
#pragma unroll
        for (int nt = 0; nt < 4; ++nt) {
          u32 w0 = pack_bf16_trunc(p[nt][0], p[nt][1]);
          u32 w1 = pack_bf16_trunc(p[nt][2], p[nt][3]);
          const int p0 = 8 * nt + 2 * quad;
          u32* dst = (u32*)Pw + (p0 >> 4) * 256 + ((p0 >> 2) & 3) * 64 +
                     l15 * 4 + (p0 & 3);
          *(uint2*)dst = make_uint2(w0, w1);
        }
        // P frags (B-operand): contiguous b128, conflict-free
        short8 pf0 = *(const short8*)&Pw[quad * 128 + l15 * 8];
        short8 pf1 = *(const short8*)&Pw[512 + quad * 128 + l15 * 8];

        // O^T += V^T P^T : lane gets O^T[d=dt*16+quad*4+reg][q=l15]
#pragma unroll
        for (int dt = 0; dt < 4; ++dt) {
          o[g][dt] = MFMA_BF16(vf[dt][0], pf0, o[g][dt]);
          o[g][dt] = MFMA_BF16(vf[dt][1], pf1, o[g][dt]);
        }
      }
    }

    // epilogue: normalize, transpose via per-wave LDS, coalesced bf16 store
#pragma unroll
    for (int g = 0; g < 2; ++g) {
      const float inv = 1.f / l_r[g];
#pragma unroll
      for (int dt = 0; dt < 4; ++dt) {
        const int d = dt * 16 + quad * 4;
        u32 w0 = pack_bf16_trunc(o[g][dt][0] * inv, o[g][dt][1] * inv);
        u32 w1 = pack_bf16_trunc(o[g][dt][2] * inv, o[g][dt][3] * inv);
        *(uint2*)&Pw[(d >> 5) * 512 + l15 * 32 + (d & 31)] = make_uint2(w0, w1);
      }
      const int qq = lane >> 2, ck = lane & 3;
      const size_t yrow = (size_t)(base_row + qg0a + g * 16 + qq);
#pragma unroll
      for (int kkd = 0; kkd < 2; ++kkd) {
        short8 vv = *(const short8*)&Pw[kkd * 512 + qq * 32 + ck * 8];
        *(short8*)(y + yrow * 1024 + h * 64 + kkd * 32 + ck * 8) = vv;
      }
    }
    __syncthreads();  // all K/V/P reads of this half done before next prologue
  }
}

// ---------------------------------------------------------------------------
// launch
// ---------------------------------------------------------------------------
extern "C" void kernel_launch(void* const* d_in, const int* in_sizes, int n_in,
                              void* d_out, int out_size, void* d_ws,
                              size_t ws_size, hipStream_t stream) {
  const float* x  = (const float*)d_in[0];   // [4,2048,1024]
  const float* wa = (const float*)d_in[1];   // [3072,1024]
  const float* wp = (const float*)d_in[2];   // [1024,1024]
  float* out = (float*)d_out;                // [4,2048,1024] fp32

  char* ws = (char*)d_ws;
  short* xb  = (short*)(ws + 0);             // 16 MB (reused as vt later)
  short* wab = (short*)(ws + 16777216);      // 6 MB
  short* wpb = (short*)(ws + 23068672);      // 2 MB
  short* qkv = (short*)(ws + 25165824);      // 48 MB
  short* yb  = (short*)(ws + 75497472);      // 16 MB
  short* vtb = xb;  // x no longer needed after GEMM1; reuse its 16 MB

  cast_bf16_kernel <<<8192, 256, 0, stream>>>(x,  xb,  8388608 / 4);
  cast_wattn_kernel<<<3072, 256, 0, stream>>>(wa, wab, 3145728 / 4);
  cast_bf16_kernel <<<1024, 256, 0, stream>>>(wp, wpb, 1048576 / 4);

  // qkv = x @ w_attn^T (q pre-scaled): M=8192 N=3072 K=1024 -> bf16
  gemm_bt_kernel<true><<<dim3(3072 / 128, 8192 / 128), 256, 0, stream>>>(
      xb, wab, (void*)qkv, 8192, 3072, 1024);

  // v-part of qkv -> vt [bh*64+d][2048]
  vtrans_kernel<<<dim3(32, 64), 256, 0, stream>>>(qkv, vtb);

  // balanced causal flash attention -> y bf16 [8192,1024]
  attn_kernel<<<dim3(64, 8), 256, 0, stream>>>(qkv, vtb, yb);

  // out = y @ w_proj^T : M=8192 N=1024 K=1024 -> fp32
  gemm_bt_kernel<false><<<dim3(1024 / 128, 8192 / 128), 256, 0, stream>>>(
      yb, wpb, (void*)out, 8192, 1024, 1024);
}

// Round 8
// 247.215 us; speedup vs baseline: 1.2353x; 1.0578x over previous
//
#include <hip/hip_runtime.h>
#include <cstdint>
#include <cstddef>

typedef __attribute__((ext_vector_type(8))) short short8;
typedef __attribute__((ext_vector_type(4))) float f32x4;
typedef unsigned int u32;

#define MFMA_BF16(a, b, c) __builtin_amdgcn_mfma_f32_16x16x32_bf16((a), (b), (c), 0, 0, 0)

// ---------------------------------------------------------------------------
// helpers
// ---------------------------------------------------------------------------
__device__ __forceinline__ void async16(const void* g, void* l) {
  __builtin_amdgcn_global_load_lds(
      (const __attribute__((address_space(1))) u32*)g,
      (__attribute__((address_space(3))) u32*)l, 16, 0, 0);
}

__device__ __forceinline__ short f2bf(float f) {
  u32 u = __builtin_bit_cast(u32, f);
  u += 0x7fffu + ((u >> 16) & 1u);  // round-to-nearest-even
  return (short)(u >> 16);
}

// truncating pack: [bf16(lo) | bf16(hi)<<16] in ONE v_perm_b32
__device__ __forceinline__ u32 pack_bf16_trunc(float lo, float hi) {
  return __builtin_amdgcn_perm(__builtin_bit_cast(u32, hi),
                               __builtin_bit_cast(u32, lo), 0x07060302u);
}

// ---------------------------------------------------------------------------
// fused cast fp32 -> bf16 for x, w_attn (q-rows pre-scaled), w_proj
// region sizes (float4 units): x 2097152, wa 786432 (first 262144 scaled), wp 262144
// ---------------------------------------------------------------------------
__global__ __launch_bounds__(256) void cast_all_kernel(
    const float* __restrict__ x, const float* __restrict__ wa,
    const float* __restrict__ wp, short* __restrict__ xb,
    short* __restrict__ wab, short* __restrict__ wpb) {
  const int i = blockIdx.x * blockDim.x + threadIdx.x;
  const float4* src;
  short4* dst;
  float sc = 1.0f;
  if (i < 2097152) {
    src = (const float4*)x + i;
    dst = (short4*)xb + i;
  } else if (i < 2883584) {
    const int j = i - 2097152;
    if (j < 262144) sc = 0.18033688011112042f;  // 1/sqrt(64)*log2(e)
    src = (const float4*)wa + j;
    dst = (short4*)wab + j;
  } else {
    const int j = i - 2883584;
    src = (const float4*)wp + j;
    dst = (short4*)wpb + j;
  }
  float4 v = *src;
  short4 r;
  r.x = f2bf(v.x * sc); r.y = f2bf(v.y * sc);
  r.z = f2bf(v.z * sc); r.w = f2bf(v.w * sc);
  *dst = r;
}

// ---------------------------------------------------------------------------
// C[M][N] = A[M][K] * Bt[N][K]^T   (bf16-as-short in, fp32 accumulate)
// r8: BK=64 — 32 MFMAs + 16 ds_reads per barrier (half the barrier/drain
// cadence of BK=32). 128x128 tile, single-buffered 32 KB LDS.
// XCD swizzle (needs gridDim.y==64): each XCD owns 8 consecutive m-tiles.
// LDS: 128 B rows, XOR-chunk placement (attn-r7 proven): slot s holds
// T[row=s>>3][chunk=(s&7)^(row&7)]; 8 consecutive lanes = one row's 8
// chunks permuted = 128 B contiguous (full coalescing); frag reads at
// chunk (kk*4+quad)^(l15&7) = 2-way bank alias = free (m136).
// ---------------------------------------------------------------------------
template <bool OUT_BF16>
__global__ __launch_bounds__(256) void gemm_bt_kernel(
    const short* __restrict__ A, const short* __restrict__ Bt,
    void* __restrict__ Cv, int M, int N, int K) {
  __shared__ __align__(16) short As[128 * 64];
  __shared__ __align__(16) short Bs[128 * 64];

  const int tid  = threadIdx.x;
  const int lane = tid & 63;
  const int wave = tid >> 6;
  const int quad = lane >> 4;
  const int l15  = lane & 15;

  // XCD swizzle (gridDim.y == 64): linear id -> (bx, by)
  const int id  = blockIdx.y * gridDim.x + blockIdx.x;
  const int xcd = id & 7;
  const int j   = id >> 3;
  const int by  = xcd * 8 + (j & 7);
  const int bx  = j >> 3;
  const int bm  = by * 128;
  const int bn  = bx * 128;

  const int wm = (wave >> 1) * 64;
  const int wn = (wave & 1) * 64;

  f32x4 acc[4][4];
#pragma unroll
  for (int i = 0; i < 4; ++i)
#pragma unroll
    for (int jj = 0; jj < 4; ++jj) acc[i][jj] = (f32x4){0.f, 0.f, 0.f, 0.f};

  // staging: 128 rows x 128 B = 1024 slots/tile, 4 slots/thread/tile.
  // slot s -> row=s>>3, chunk=(s&7)^(row&7); dst shorts s*8.
  int srow[4], scol[4];
#pragma unroll
  for (int it = 0; it < 4; ++it) {
    const int s = tid + it * 256;
    srow[it] = s >> 3;
    scol[it] = ((s & 7) ^ (srow[it] & 7)) * 8;
  }
  const int xk = l15 & 7;  // frag-read chunk XOR

  for (int k0 = 0; k0 < K; k0 += 64) {
    __syncthreads();
#pragma unroll
    for (int it = 0; it < 4; ++it) {
      const int s = tid + it * 256;
      async16(A  + (size_t)(bm + srow[it]) * K + k0 + scol[it], &As[s * 8]);
      async16(Bt + (size_t)(bn + srow[it]) * K + k0 + scol[it], &Bs[s * 8]);
    }
    __syncthreads();

    short8 af[4][2], bf[4][2];
#pragma unroll
    for (int mt = 0; mt < 4; ++mt) {
      const int ra = (wm + mt * 16 + l15) * 64;
      af[mt][0] = *(const short8*)&As[ra + ((quad) ^ xk) * 8];
      af[mt][1] = *(const short8*)&As[ra + ((4 + quad) ^ xk) * 8];
    }
#pragma unroll
    for (int nt = 0; nt < 4; ++nt) {
      const int rb = (wn + nt * 16 + l15) * 64;
      bf[nt][0] = *(const short8*)&Bs[rb + ((quad) ^ xk) * 8];
      bf[nt][1] = *(const short8*)&Bs[rb + ((4 + quad) ^ xk) * 8];
    }
#pragma unroll
    for (int kk = 0; kk < 2; ++kk)
#pragma unroll
      for (int mt = 0; mt < 4; ++mt)
#pragma unroll
        for (int nt = 0; nt < 4; ++nt)
          acc[mt][nt] = MFMA_BF16(af[mt][kk], bf[nt][kk], acc[mt][nt]);
  }

  // epilogue: C/D layout col = lane&15, row = quad*4 + reg
#pragma unroll
  for (int mt = 0; mt < 4; ++mt) {
    const int r0e = bm + wm + mt * 16 + quad * 4;
#pragma unroll
    for (int nt = 0; nt < 4; ++nt) {
      const int c = bn + wn + nt * 16 + l15;
#pragma unroll
      for (int reg = 0; reg < 4; ++reg) {
        float v = acc[mt][nt][reg];
        if (OUT_BF16)
          ((short*)Cv)[(size_t)(r0e + reg) * N + c] = f2bf(v);
        else
          ((float*)Cv)[(size_t)(r0e + reg) * N + c] = v;
      }
    }
  }
}

// ---------------------------------------------------------------------------
// V transpose: qkv v-part [B*T][h*64+d] -> vt [bh*64+d][T]   (bf16 shorts)
// (unchanged — known-good)
// ---------------------------------------------------------------------------
__global__ __launch_bounds__(256) void vtrans_kernel(
    const short* __restrict__ qkv, short* __restrict__ vt) {
  __shared__ __align__(16) short Ts[64 * 80];
  const int t0 = blockIdx.x * 64;
  const int bh = blockIdx.y;
  const int b = bh >> 4, h = bh & 15;
  const int tid = threadIdx.x;
#pragma unroll
  for (int it = 0; it < 2; ++it) {
    const int ci = tid + it * 256;
    const int t = ci >> 3, cw = ci & 7;
    short8 v = *(const short8*)(qkv + (size_t)(b * 2048 + t0 + t) * 3072 +
                                2048 + h * 64 + cw * 8);
    *(short8*)&Ts[t * 80 + cw * 8] = v;
  }
  __syncthreads();
#pragma unroll
  for (int it = 0; it < 2; ++it) {
    const int ci = tid + it * 256;
    const int d = ci >> 3, c2 = ci & 7;
    short tmp[8];
#pragma unroll
    for (int j = 0; j < 8; ++j) tmp[j] = Ts[(c2 * 8 + j) * 80 + d];
    *(short8*)(vt + (size_t)(bh * 64 + d) * 2048 + t0 + c2 * 8) =
        *(short8*)tmp;
  }
}

// ---------------------------------------------------------------------------
// Causal flash attention (unchanged from r7 — known-good).
// ---------------------------------------------------------------------------
__global__ __launch_bounds__(256, 2) void attn_kernel(
    const short* __restrict__ qkv, const short* __restrict__ vt,
    short* __restrict__ y) {
  __shared__ __align__(16) short Ks[2][4096];  // [buf][row t][64 d]
  __shared__ __align__(16) short Vs[2][4096];  // [buf][row d][64 t]
  __shared__ __align__(16) short Ps[4][1024];  // per-wave P / epilogue

  const int bh    = blockIdx.x;     // 0..63  (XCD = bh % 8 for all pairi)
  const int pairi = blockIdx.y;     // 0..7
  const int b = bh >> 4, h = bh & 15;
  const int tid  = threadIdx.x;
  const int lane = tid & 63;
  const int wave = tid >> 6;
  const int quad = lane >> 4, l15 = lane & 15;
  const int base_row = b * 2048;
  short* Pw = &Ps[wave][0];

  // staging: slot s -> row=s>>3, chunk=(s&7)^(row&7); dst shorts s*8
  const int s0 = tid, s1 = tid + 256;
  const int r0s = s0 >> 3, c0s = (s0 & 7) ^ (r0s & 7);
  const int r1s = s1 >> 3, c1s = (s1 & 7) ^ (r1s & 7);
  const short* kbase0 = qkv + (size_t)(base_row + r0s) * 3072 + 1024 + h * 64 + c0s * 8;
  const short* kbase1 = qkv + (size_t)(base_row + r1s) * 3072 + 1024 + h * 64 + c1s * 8;
  const short* vbase0 = vt + (size_t)(bh * 64 + r0s) * 2048 + c0s * 8;
  const short* vbase1 = vt + (size_t)(bh * 64 + r1s) * 2048 + c1s * 8;

  const int xk = l15 & 7;  // frag-read chunk XOR

  for (int half = 0; half < 2; ++half) {
    const int qi  = half ? (15 - pairi) : pairi;
    const int r0  = qi * 128;
    const int nkt = 2 * qi + 2;
    const int qg0a = r0 + wave * 32;   // group 0 q-base (seq-relative)

    // Q fragments (B-operand): lane holds Q[q=l15][d=quad*8..+7] per half
    short8 qf[2][2];
#pragma unroll
    for (int g = 0; g < 2; ++g) {
      const short* qp = qkv +
          (size_t)(base_row + qg0a + g * 16 + l15) * 3072 + h * 64 + quad * 8;
      qf[g][0] = *(const short8*)qp;
      qf[g][1] = *(const short8*)(qp + 32);
    }
    float l_r[2] = {0.f, 0.f};
    f32x4 o[2][4];
#pragma unroll
    for (int g = 0; g < 2; ++g)
#pragma unroll
      for (int dt = 0; dt < 4; ++dt) o[g][dt] = (f32x4){0.f, 0.f, 0.f, 0.f};

    // prologue: stage kv-tile 0 into buffer 0
    async16(kbase0, &Ks[0][s0 * 8]);
    async16(kbase1, &Ks[0][s1 * 8]);
    async16(vbase0, &Vs[0][s0 * 8]);
    async16(vbase1, &Vs[0][s1 * 8]);

    for (int kt = 0; kt < nkt; ++kt) {
      const int kvb = kt * 64;
      __syncthreads();  // drains vmcnt -> buf[kt&1] ready; prev reads done

      // prefetch next tile into the other buffer
      if (kt + 1 < nkt) {
        const int nb = (kt + 1) & 1;
        const size_t koff = (size_t)(kvb + 64) * 3072;
        async16(kbase0 + koff, &Ks[nb][s0 * 8]);
        async16(kbase1 + koff, &Ks[nb][s1 * 8]);
        async16(vbase0 + kvb + 64, &Vs[nb][s0 * 8]);
        async16(vbase1 + kvb + 64, &Vs[nb][s1 * 8]);
      }
      const short* Kb = &Ks[kt & 1][0];
      const short* Vb = &Vs[kt & 1][0];

      // K frags (A-operand): row t=nt*16+l15, chunk (kk*4+quad)^xk
      short8 kf[4][2];
#pragma unroll
      for (int nt = 0; nt < 4; ++nt) {
        kf[nt][0] = *(const short8*)&Kb[(nt * 16 + l15) * 64 + ((quad) ^ xk) * 8];
        kf[nt][1] = *(const short8*)&Kb[(nt * 16 + l15) * 64 + ((4 + quad) ^ xk) * 8];
      }
      // V frags (A-operand): hoisted — read ONCE, shared by both groups
      short8 vf[4][2];
#pragma unroll
      for (int dt = 0; dt < 4; ++dt) {
        vf[dt][0] = *(const short8*)&Vb[(dt * 16 + l15) * 64 + ((quad) ^ xk) * 8];
        vf[dt][1] = *(const short8*)&Vb[(dt * 16 + l15) * 64 + ((4 + quad) ^ xk) * 8];
      }

#pragma unroll
      for (int g = 0; g < 2; ++g) {
        const int qg0 = qg0a + g * 16;
        if (kvb > qg0 + 15) continue;  // group fully masked

        // S^T = K Q^T : lane gets S^T[kv=nt*16+quad*4+reg][q=l15]
        f32x4 s[4];
#pragma unroll
        for (int nt = 0; nt < 4; ++nt) {
          s[nt] = MFMA_BF16(kf[nt][0], qf[g][0], ((f32x4){0.f, 0.f, 0.f, 0.f}));
          s[nt] = MFMA_BF16(kf[nt][1], qf[g][1], s[nt]);
        }

        // p = exp2(s); mask only on diagonal tiles
        float p[4][4];
        if (kvb + 64 <= qg0) {
#pragma unroll
          for (int nt = 0; nt < 4; ++nt)
#pragma unroll
            for (int r = 0; r < 4; ++r)
              p[nt][r] = __builtin_amdgcn_exp2f(s[nt][r]);
        } else {
          const int qrel = qg0 + l15 - kvb;
#pragma unroll
          for (int nt = 0; nt < 4; ++nt)
#pragma unroll
            for (int r = 0; r < 4; ++r) {
              const int kvl = nt * 16 + quad * 4 + r;
              p[nt][r] = (kvl <= qrel) ? __builtin_amdgcn_exp2f(s[nt][r]) : 0.f;
            }
        }

        // row sum: 15 in-lane adds + 2 cross-quad shuffles
        float rs = ((p[0][0] + p[0][1]) + (p[0][2] + p[0][3])) +
                   ((p[1][0] + p[1][1]) + (p[1][2] + p[1][3])) +
                   ((p[2][0] + p[2][1]) + (p[2][2] + p[2][3])) +
                   ((p[3][0] + p[3][1]) + (p[3][2] + p[3][3]));
        rs += __shfl_xor(rs, 16);
        rs += __shfl_xor(rs, 32);
        l_r[g] += rs;

        // P -> LDS, layout [f][chunk][q]x16B; pair p0 = 8nt+2quad
#pragma unroll
        for (int nt = 0; nt < 4; ++nt) {
          u32 w0 = pack_bf16_trunc(p[nt][0], p[nt][1]);
          u32 w1 = pack_bf16_trunc(p[nt][2], p[nt][3]);
          const int p0 = 8 * nt + 2 * quad;
          u32* dst = (u32*)Pw + (p0 >> 4) * 256 + ((p0 >> 2) & 3) * 64 +
                     l15 * 4 + (p0 & 3);
          *(uint2*)dst = make_uint2(w0, w1);
        }
        // P frags (B-operand): contiguous b128, conflict-free
        short8 pf0 = *(const short8*)&Pw[quad * 128 + l15 * 8];
        short8 pf1 = *(const short8*)&Pw[512 + quad * 128 + l15 * 8];

        // O^T += V^T P^T : lane gets O^T[d=dt*16+quad*4+reg][q=l15]
#pragma unroll
        for (int dt = 0; dt < 4; ++dt) {
          o[g][dt] = MFMA_BF16(vf[dt][0], pf0, o[g][dt]);
          o[g][dt] = MFMA_BF16(vf[dt][1], pf1, o[g][dt]);
        }
      }
    }

    // epilogue: normalize, transpose via per-wave LDS, coalesced bf16 store
#pragma unroll
    for (int g = 0; g < 2; ++g) {
      const float inv = 1.f / l_r[g];
#pragma unroll
      for (int dt = 0; dt < 4; ++dt) {
        const int d = dt * 16 + quad * 4;
        u32 w0 = pack_bf16_trunc(o[g][dt][0] * inv, o[g][dt][1] * inv);
        u32 w1 = pack_bf16_trunc(o[g][dt][2] * inv, o[g][dt][3] * inv);
        *(uint2*)&Pw[(d >> 5) * 512 + l15 * 32 + (d & 31)] = make_uint2(w0, w1);
      }
      const int qq = lane >> 2, ck = lane & 3;
      const size_t yrow = (size_t)(base_row + qg0a + g * 16 + qq);
#pragma unroll
      for (int kkd = 0; kkd < 2; ++kkd) {
        short8 vv = *(const short8*)&Pw[kkd * 512 + qq * 32 + ck * 8];
        *(short8*)(y + yrow * 1024 + h * 64 + kkd * 32 + ck * 8) = vv;
      }
    }
    __syncthreads();  // all K/V/P reads of this half done before next prologue
  }
}

// ---------------------------------------------------------------------------
// launch
// ---------------------------------------------------------------------------
extern "C" void kernel_launch(void* const* d_in, const int* in_sizes, int n_in,
                              void* d_out, int out_size, void* d_ws,
                              size_t ws_size, hipStream_t stream) {
  const float* x  = (const float*)d_in[0];   // [4,2048,1024]
  const float* wa = (const float*)d_in[1];   // [3072,1024]
  const float* wp = (const float*)d_in[2];   // [1024,1024]
  float* out = (float*)d_out;                // [4,2048,1024] fp32

  char* ws = (char*)d_ws;
  short* xb  = (short*)(ws + 0);             // 16 MB (reused as vt later)
  short* wab = (short*)(ws + 16777216);      // 6 MB
  short* wpb = (short*)(ws + 23068672);      // 2 MB
  short* qkv = (short*)(ws + 25165824);      // 48 MB
  short* yb  = (short*)(ws + 75497472);      // 16 MB
  short* vtb = xb;  // x no longer needed after GEMM1; reuse its 16 MB

  // fused casts (x, wa with q-scale, wp): 3145728 float4 elems
  cast_all_kernel<<<12288, 256, 0, stream>>>(x, wa, wp, xb, wab, wpb);

  // qkv = x @ w_attn^T (q pre-scaled): M=8192 N=3072 K=1024 -> bf16
  gemm_bt_kernel<true><<<dim3(3072 / 128, 8192 / 128), 256, 0, stream>>>(
      xb, wab, (void*)qkv, 8192, 3072, 1024);

  // v-part of qkv -> vt [bh*64+d][2048]
  vtrans_kernel<<<dim3(32, 64), 256, 0, stream>>>(qkv, vtb);

  // balanced causal flash attention -> y bf16 [8192,1024]
  attn_kernel<<<dim3(64, 8), 256, 0, stream>>>(qkv, vtb, yb);

  // out = y @ w_proj^T : M=8192 N=1024 K=1024 -> fp32
  gemm_bt_kernel<false><<<dim3(1024 / 128, 8192 / 128), 256, 0, stream>>>(
      yb, wpb, (void*)out, 8192, 1024, 1024);
}